// Round 3
// baseline (208.596 us; speedup 1.0000x reference)
//
#include <hip/hip_runtime.h>
#include <stdint.h>

typedef __bf16 bf16_t;
typedef __bf16 bf16x8 __attribute__((ext_vector_type(8)));
typedef float f32x4 __attribute__((ext_vector_type(4)));
typedef float f32x16 __attribute__((ext_vector_type(16)));

#define DEV __device__ __forceinline__

DEV void gload_lds16(const void* g, void* lds) {
  __builtin_amdgcn_global_load_lds(
      (const __attribute__((address_space(1))) uint32_t*)g,
      (__attribute__((address_space(3))) uint32_t*)lds, 16, 0, 0);
}

DEV float fexp2(float x) {
#if __has_builtin(__builtin_amdgcn_exp2f)
  return __builtin_amdgcn_exp2f(x);
#else
  return exp2f(x);
#endif
}

DEV uint32_t pk_bf16(float a, float b) {
  uint32_t lo = (uint32_t)__builtin_bit_cast(uint16_t, (bf16_t)a);
  uint32_t hi = (uint32_t)__builtin_bit_cast(uint16_t, (bf16_t)b);
  return lo | (hi << 16);
}

// ---------------------------------------------------------------- K0: hs -> bf16
__global__ __launch_bounds__(256) void cvt_hs(const float* __restrict__ x,
                                              bf16_t* __restrict__ y) {
  int i = blockIdx.x * 256 + threadIdx.x;
  float4 v = ((const float4*)x)[i];
  ((uint2*)y)[i] = make_uint2(pk_bf16(v.x, v.y), pk_bf16(v.z, v.w));
}

// ------------------------------------------- K1: W[k][n] (x3) -> WT[n][k] bf16
__global__ __launch_bounds__(256) void cvt_w(const float* __restrict__ Wq,
                                             const float* __restrict__ Wk,
                                             const float* __restrict__ Wv,
                                             bf16_t* __restrict__ WT) {
  __shared__ float T[32][36];
  const int bx = blockIdx.x;   // n tile 0..71 (over 2304)
  const int by = blockIdx.y;   // k tile 0..23 (over 768)
  const int p = bx / 24;
  const float* W = (p == 0) ? Wq : ((p == 1) ? Wk : Wv);
  const int n0 = bx * 32, nn0 = n0 - p * 768, k0 = by * 32;
  const int t = threadIdx.x;
  {
    int r = t >> 3, c4 = (t & 7) * 4;
    float4 v = *(const float4*)&W[(size_t)(k0 + r) * 768 + nn0 + c4];
    T[r][c4 + 0] = v.x; T[r][c4 + 1] = v.y; T[r][c4 + 2] = v.z; T[r][c4 + 3] = v.w;
  }
  __syncthreads();
  {
    int nr = t >> 3, kc = (t & 7) * 4;
    uint32_t lo = pk_bf16(T[kc + 0][nr], T[kc + 1][nr]);
    uint32_t hi = pk_bf16(T[kc + 2][nr], T[kc + 3][nr]);
    *(uint2*)&WT[(size_t)(n0 + nr) * 768 + k0 + kc] = make_uint2(lo, hi);
  }
}

// ------------------------------------------------- K2: C[4096,2304] = A @ W (+b)
// m97-style core. Epilogue: C tile through LDS (padded) -> coalesced 16B stores.
// Q/K stored [bh][s][64]; V stored pre-transposed VT[bh][d][2048].
__global__ __launch_bounds__(256) void gemm_qkv(
    const bf16_t* __restrict__ A, const bf16_t* __restrict__ Wt,
    const float* __restrict__ bq, const float* __restrict__ bk,
    const float* __restrict__ bv, bf16_t* __restrict__ Qo,
    bf16_t* __restrict__ Ko, bf16_t* __restrict__ VTo) {
  __shared__ __align__(16) char smem[34816];  // union: As+Bs (32KB) | Cs 128x136
  bf16_t* As = (bf16_t*)smem;
  bf16_t* Bs = As + 128 * 64;
  bf16_t* Cs = (bf16_t*)smem;
  const int bx = blockIdx.x;  // 0..17 (n)
  const int by = blockIdx.y;  // 0..31 (m)
  const int m0 = by * 128, n0 = bx * 128;
  const int tid = threadIdx.x, w = tid >> 6, lane = tid & 63;
  const int mw = (w & 1) * 64, nw = (w >> 1) * 64;
  const int quad = lane >> 4, col = lane & 15;

  f32x4 acc[4][4];
  for (int i = 0; i < 4; i++)
    for (int j = 0; j < 4; j++) acc[i][j] = (f32x4){0.f, 0.f, 0.f, 0.f};

  const int srow = w * 32 + (lane >> 3);
  const int scol = (lane & 7) * 8;
  const bf16_t* ag = A + (size_t)(m0 + srow) * 768 + scol;
  const bf16_t* bg = Wt + (size_t)(n0 + srow) * 768 + scol;

  for (int kk = 0; kk < 12; ++kk) {
    const int k0 = kk * 64;
    __syncthreads();
#pragma unroll
    for (int i = 0; i < 4; i++) {
      gload_lds16(ag + (size_t)i * 8 * 768 + k0, As + (w * 32 + i * 8) * 64);
      gload_lds16(bg + (size_t)i * 8 * 768 + k0, Bs + (w * 32 + i * 8) * 64);
    }
    __syncthreads();
#pragma unroll
    for (int ks = 0; ks < 2; ++ks) {
      bf16x8 af[4], bf[4];
#pragma unroll
      for (int mt = 0; mt < 4; ++mt)
        af[mt] = *(const bf16x8*)&As[(mw + mt * 16 + col) * 64 + ks * 32 + quad * 8];
#pragma unroll
      for (int nt = 0; nt < 4; ++nt)
        bf[nt] = *(const bf16x8*)&Bs[(nw + nt * 16 + col) * 64 + ks * 32 + quad * 8];
#pragma unroll
      for (int mt = 0; mt < 4; ++mt)
#pragma unroll
        for (int nt = 0; nt < 4; ++nt)
          acc[mt][nt] = __builtin_amdgcn_mfma_f32_16x16x32_bf16(
              af[mt], bf[nt], acc[mt][nt], 0, 0, 0);
    }
  }

  const int p = bx / 6;
  const float* bp = (p == 0) ? bq : ((p == 1) ? bk : bv);
  const int bb0 = m0 >> 11, s0 = m0 & 2047;
  __syncthreads();  // staging reads done; reuse LDS as Cs
  if (p < 2) {
    // Cs[m][n] (pad 8): coalesced row stores into Q/K [bh][s][64]
#pragma unroll
    for (int nt = 0; nt < 4; nt++) {
      int n = nw + nt * 16 + col;
      float bias = bp[n0 + n - p * 768];
#pragma unroll
      for (int mt = 0; mt < 4; mt++)
#pragma unroll
        for (int r = 0; r < 4; r++) {
          int m = mw + mt * 16 + quad * 4 + r;
          Cs[m * 136 + n] = (bf16_t)(acc[mt][nt][r] + bias);
        }
    }
    __syncthreads();
    bf16_t* dst = (p == 0) ? Qo : Ko;
#pragma unroll
    for (int i = 0; i < 8; i++) {
      int idx = i * 256 + tid;
      int m = idx >> 4, c = idx & 15;
      bf16x8 v = *(const bf16x8*)&Cs[m * 136 + c * 8];
      int nn = n0 - p * 768 + c * 8;
      int hq = nn >> 6, hd = nn & 63;
      *(bf16x8*)&dst[(size_t)((bb0 * 12 + hq) * 2048 + s0 + m) * 64 + hd] = v;
    }
  } else {
    // Cs[n][m] (pad 8): coalesced row stores into VT[bh][d][2048]
#pragma unroll
    for (int nt = 0; nt < 4; nt++) {
      int n = nw + nt * 16 + col;
      float bias = bp[n0 + n - 1536];
#pragma unroll
      for (int mt = 0; mt < 4; mt++)
#pragma unroll
        for (int r = 0; r < 4; r++) {
          int m = mw + mt * 16 + quad * 4 + r;
          Cs[n * 136 + m] = (bf16_t)(acc[mt][nt][r] + bias);
        }
    }
    __syncthreads();
#pragma unroll
    for (int i = 0; i < 8; i++) {
      int idx = i * 256 + tid;
      int n = idx >> 4, c = idx & 15;
      bf16x8 v = *(const bf16x8*)&Cs[n * 136 + c * 8];
      int nn = n0 - 1536 + n;
      int hq = nn >> 6, hd = nn & 63;
      *(bf16x8*)&VTo[((size_t)(bb0 * 12 + hq) * 64 + hd) * 2048 + s0 + c * 8] = v;
    }
  }
}

// ---------------------------------------------------------------- K3: attention
// v3: 2 waves/WG, 64 q/wave. S^T = K@Q^T; O accumulated TRANSPOSED
// (O^T = V^T @ P^T) so softmax stats & rescale are per-lane (no bpermute).
// K/V staging double-buffered, prefetch issued before compute, 1 barrier/iter.
__global__ __launch_bounds__(128, 2) void attn(const bf16_t* __restrict__ Q,
                                               const bf16_t* __restrict__ K,
                                               const bf16_t* __restrict__ VT,
                                               float* __restrict__ out) {
  __shared__ bf16_t Kl[2][64 * 64];   // [key][d], 16B chunks XOR-swizzled
  __shared__ bf16_t Vl[2][64 * 64];   // [d][key], same swizzle
  __shared__ bf16_t Pl[2][64 * 64];   // per-wave [q][key]; reused as fp32 O-scratch
  const int qt = blockIdx.x;  // 0..15
  const int bh = blockIdx.y;  // 0..23
  const int b = bh / 12, head = bh % 12;
  const int tid = threadIdx.x, wv = tid >> 6, lane = tid & 63;
  const int lq = lane & 31, half = lane >> 5;
  const int q0 = qt * 128 + wv * 64;

  bf16x8 qf[2][4];  // B-frags of Q^T, register-resident: [q-subtile][ks]
#pragma unroll
  for (int qt2 = 0; qt2 < 2; qt2++)
#pragma unroll
    for (int ks = 0; ks < 4; ks++)
      qf[qt2][ks] = *(const bf16x8*)&Q[(size_t)(bh * 2048 + q0 + qt2 * 32 + lq) * 64 +
                                       ks * 16 + half * 8];

  f32x16 oacc[2][2];  // [d-tile][q-subtile], O^T layout: col=q, rows=d
  for (int i = 0; i < 16; i++) {
    oacc[0][0][i] = 0.f; oacc[0][1][i] = 0.f;
    oacc[1][0][i] = 0.f; oacc[1][1][i] = 0.f;
  }
  float m_run[2] = {-1e30f, -1e30f}, l_run[2] = {0.f, 0.f};

  const bf16_t* gK = K + (size_t)bh * 2048 * 64;
  const bf16_t* gV = VT + (size_t)bh * 64 * 2048;
  const int srow = lane >> 3, scc = lane & 7;

  auto stage = [&](int kb, int bb) {
    if (wv == 0) {
#pragma unroll
      for (int i = 0; i < 8; i++) {
        int row = i * 8 + srow, cg = scc ^ (row & 7);
        gload_lds16(gK + (size_t)(kb * 64 + row) * 64 + cg * 8, &Kl[bb][i * 512]);
      }
    } else {
#pragma unroll
      for (int i = 0; i < 8; i++) {
        int row = i * 8 + srow, cg = scc ^ (row & 7);
        gload_lds16(gV + (size_t)row * 2048 + kb * 64 + cg * 8, &Vl[bb][i * 512]);
      }
    }
  };

  stage(0, 0);
  __syncthreads();

  for (int kb = 0; kb < 32; ++kb) {
    const int bb = kb & 1;
    if (kb < 31) stage(kb + 1, bb ^ 1);  // prefetch: in flight during compute

    // S^T[key][q] = K_blk @ Q^T  (A = K frags, B = qf)
    f32x16 sacc[2][2];  // [key-tile][q-subtile]
    for (int i = 0; i < 16; i++) {
      sacc[0][0][i] = 0.f; sacc[0][1][i] = 0.f;
      sacc[1][0][i] = 0.f; sacc[1][1][i] = 0.f;
    }
#pragma unroll
    for (int t = 0; t < 2; t++) {
      const int row = t * 32 + lq;
#pragma unroll
      for (int ks = 0; ks < 4; ++ks) {
        bf16x8 kf = *(const bf16x8*)&Kl[bb][row * 64 + (((2 * ks + half) ^ (row & 7)) * 8)];
        sacc[t][0] = __builtin_amdgcn_mfma_f32_32x32x16_bf16(kf, qf[0][ks], sacc[t][0], 0, 0, 0);
        sacc[t][1] = __builtin_amdgcn_mfma_f32_32x32x16_bf16(kf, qf[1][ks], sacc[t][1], 0, 0, 0);
      }
    }

    const float cc = 0.18033688011112042f;  // log2(e)/sqrt(64)
#pragma unroll
    for (int qt2 = 0; qt2 < 2; qt2++) {
      float mb = -1e30f;
#pragma unroll
      for (int t = 0; t < 2; t++)
#pragma unroll
        for (int r = 0; r < 16; r++) mb = fmaxf(mb, sacc[t][qt2][r]);
      mb = fmaxf(mb, __shfl_xor(mb, 32));
      const float mnew = fmaxf(m_run[qt2], mb);
      const float alpha = fexp2((m_run[qt2] - mnew) * cc);
      float ps = 0.f;
#pragma unroll
      for (int t = 0; t < 2; t++)
#pragma unroll
        for (int r = 0; r < 16; r++) {
          float pv = fexp2((sacc[t][qt2][r] - mnew) * cc);
          sacc[t][qt2][r] = pv;
          ps += pv;
        }
      ps += __shfl_xor(ps, 32);
      l_run[qt2] = l_run[qt2] * alpha + ps;
      m_run[qt2] = mnew;

      // P -> Pl[wv] rows q = qt2*32+lq (keys for (t,a2): 32t+8a2+4half+0..3)
      const int q = qt2 * 32 + lq;
      char* pw = (char*)&Pl[wv][0] + q * 128 + half * 8;
#pragma unroll
      for (int t = 0; t < 2; t++)
#pragma unroll
        for (int a2 = 0; a2 < 4; a2++) {
          uint32_t lo = pk_bf16(sacc[t][qt2][4 * a2 + 0], sacc[t][qt2][4 * a2 + 1]);
          uint32_t hi = pk_bf16(sacc[t][qt2][4 * a2 + 2], sacc[t][qt2][4 * a2 + 3]);
          *(uint2*)(pw + (((4 * t + a2) ^ (q & 7)) * 16)) = make_uint2(lo, hi);
        }

      // per-lane rescale (no bpermute: O^T cols = q = this lane)
#pragma unroll
      for (int dt = 0; dt < 2; dt++)
#pragma unroll
        for (int r = 0; r < 16; r++) oacc[dt][qt2][r] *= alpha;
    }

    // O^T += V^T @ P^T  (A = V frags, B = P frags)
#pragma unroll
    for (int ks = 0; ks < 4; ks++) {
      bf16x8 pb[2];
#pragma unroll
      for (int qt2 = 0; qt2 < 2; qt2++) {
        const int q = qt2 * 32 + lq;
        pb[qt2] = *(const bf16x8*)&Pl[wv][q * 64 + (((2 * ks + half) ^ (q & 7)) * 8)];
      }
#pragma unroll
      for (int dt = 0; dt < 2; dt++) {
        const int vr = dt * 32 + lq;
        bf16x8 vf = *(const bf16x8*)&Vl[bb][vr * 64 + (((2 * ks + half) ^ (vr & 7)) * 8)];
        oacc[dt][0] = __builtin_amdgcn_mfma_f32_32x32x16_bf16(vf, pb[0], oacc[dt][0], 0, 0, 0);
        oacc[dt][1] = __builtin_amdgcn_mfma_f32_32x32x16_bf16(vf, pb[1], oacc[dt][1], 0, 0, 0);
      }
    }
    __syncthreads();  // drains prefetch (had full compute phase to land) + guards bufs
  }

  // epilogue: O^T -> out[q][d] via per-wave LDS transpose, coalesced f32x4 stores
  const float linv[2] = {1.0f / l_run[0], 1.0f / l_run[1]};
  float* Of = (float*)&Pl[wv][0];  // 64q x 32d fp32, chunk-swizzled
  float* ob = out + ((size_t)b * 2048 + q0) * 768 + head * 64;
#pragma unroll
  for (int dt = 0; dt < 2; dt++) {
#pragma unroll
    for (int qt2 = 0; qt2 < 2; qt2++)
#pragma unroll
      for (int r = 0; r < 16; r++) {
        int d = (r & 3) + 8 * (r >> 2) + 4 * half;
        int q = qt2 * 32 + lq;
        Of[q * 32 + (((d >> 2) ^ (q & 7)) * 4) + (d & 3)] = oacc[dt][qt2][r] * linv[qt2];
      }
    // per-wave LDS; DS pipe is in-order per wave, compiler inserts lgkm waits
#pragma unroll
    for (int i = 0; i < 8; i++) {
      int idx = i * 64 + lane;
      int q = idx >> 3, pch = idx & 7;
      f32x4 v = *(f32x4*)&Of[q * 32 + pch * 4];
      int c = pch ^ (q & 7);
      *(f32x4*)&ob[(size_t)q * 768 + dt * 32 + c * 4] = v;
    }
  }
}

// -------------------------------------------------------------------- launcher
extern "C" void kernel_launch(void* const* d_in, const int* in_sizes, int n_in,
                              void* d_out, int out_size, void* d_ws, size_t ws_size,
                              hipStream_t stream) {
  const float* hs = (const float*)d_in[0];
  const float* Wq = (const float*)d_in[1];
  const float* bq = (const float*)d_in[2];
  const float* Wk = (const float*)d_in[3];
  const float* bk = (const float*)d_in[4];
  const float* Wv = (const float*)d_in[5];
  const float* bv = (const float*)d_in[6];
  float* out = (float*)d_out;

  char* w = (char*)d_ws;
  bf16_t* hsb = (bf16_t*)w; w += (size_t)4096 * 768 * 2;
  bf16_t* wtb = (bf16_t*)w; w += (size_t)2304 * 768 * 2;
  bf16_t* Qb  = (bf16_t*)w; w += (size_t)24 * 2048 * 64 * 2;
  bf16_t* Kb  = (bf16_t*)w; w += (size_t)24 * 2048 * 64 * 2;
  bf16_t* VTb = (bf16_t*)w;

  hipLaunchKernelGGL(cvt_hs, dim3(3072), dim3(256), 0, stream, hs, hsb);
  hipLaunchKernelGGL(cvt_w, dim3(72, 24), dim3(256), 0, stream, Wq, Wk, Wv, wtb);
  hipLaunchKernelGGL(gemm_qkv, dim3(18, 32), dim3(256), 0, stream, hsb, wtb, bq,
                     bk, bv, Qb, Kb, VTb);
  hipLaunchKernelGGL(attn, dim3(16, 24), dim3(128), 0, stream, Qb, Kb, VTb, out);
}